// Round 6
// baseline (341.937 us; speedup 1.0000x reference)
//
#include <hip/hip_runtime.h>

typedef unsigned int u32;
typedef unsigned short u16;
typedef __attribute__((ext_vector_type(8))) short s8v;
typedef __attribute__((ext_vector_type(8))) __bf16 b8v;
typedef __attribute__((ext_vector_type(4))) float f4v;
typedef __attribute__((ext_vector_type(16))) float f32x16;
typedef __attribute__((ext_vector_type(4))) u32 u32x4;
typedef __attribute__((ext_vector_type(2))) u32 u32x2;

#define DEV static __device__ __forceinline__

DEV u32 cvtpk(float a, float b){ u32 r; asm("v_cvt_pk_bf16_f32 %0, %1, %2" : "=v"(r) : "v"(a), "v"(b)); return r; }
DEV u16 f2bf(float x){ return (u16)(cvtpk(x, x) & 0xffffu); }
DEV float bf2f(u16 u){ return __builtin_bit_cast(float, ((u32)u) << 16); }

DEV f4v mfma16(s8v a, s8v b, f4v c){
  return __builtin_amdgcn_mfma_f32_16x16x32_bf16(__builtin_bit_cast(b8v, a), __builtin_bit_cast(b8v, b), c, 0, 0, 0);
}
DEV f32x16 mfma32(s8v a, s8v b, f32x16 c){
  return __builtin_amdgcn_mfma_f32_32x32x16_bf16(__builtin_bit_cast(b8v, a), __builtin_bit_cast(b8v, b), c, 0, 0, 0);
}

DEV void gl_lds16(const void* g, void* l){
  __builtin_amdgcn_global_load_lds((const __attribute__((address_space(1))) u32*)g,
                                   (__attribute__((address_space(3))) u32*)l, 16, 0, 0);
}

// ---------------- prep: X fp32 -> bf16 ----------------
__global__ __launch_bounds__(256) void k_prepx(const float* __restrict__ x, u16* __restrict__ xb, int n){
  int i = (blockIdx.x * 256 + threadIdx.x) * 8;
  if (i >= n) return;
  float4 a = *(const float4*)(x + i);
  float4 b = *(const float4*)(x + i + 4);
  u32x4 o;
  o.x = cvtpk(a.x, a.y); o.y = cvtpk(a.z, a.w);
  o.z = cvtpk(b.x, b.y); o.w = cvtpk(b.z, b.w);
  *(u32x4*)(xb + i) = o;
}

// ---------------- prep: transpose fp32 [K][N] -> bf16 [N][K] (ldd) ----------------
__global__ __launch_bounds__(256) void k_transpose(const float* __restrict__ src, u16* __restrict__ dst,
                                                   int K, int N, int ldd){
  __shared__ float t[32][33];
  int nt = N >> 5;
  int k0 = (blockIdx.x / nt) << 5, n0 = (blockIdx.x % nt) << 5;
  int col = threadIdx.x & 31, rw = threadIdx.x >> 5;
  #pragma unroll
  for (int i = 0; i < 4; i++){ int r = rw + i * 8; t[r][col] = src[(k0 + r) * N + n0 + col]; }
  __syncthreads();
  #pragma unroll
  for (int i = 0; i < 4; i++){ int r = rw + i * 8; dst[(n0 + r) * ldd + k0 + col] = f2bf(t[col][r]); }
}

// ---------------- GEMM: C[M,N] = A[M,K] * Bt[N,K]^T, bf16 in, bf16 or f32 out ----------------
template<int OUTF32>
__global__ __launch_bounds__(256) void k_gemm(const u16* __restrict__ A, const u16* __restrict__ Bt,
                                              void* __restrict__ Cv, int M, int N, int K){
  __shared__ u16 sA[128 * 64];
  __shared__ u16 sB[128 * 64];
  int tid = threadIdx.x, w = tid >> 6, lane = tid & 63, g = lane >> 4, c = lane & 15;
  int n0 = blockIdx.x << 7, m0 = blockIdx.y << 7;
  int wr = w >> 1, wc = w & 1;
  f4v acc[4][4] = {};
  int srow = lane >> 3;
  int sslot = (lane & 7) ^ srow;
  const u16* Abase = A + (m0 + srow) * K + sslot * 8;
  const u16* Bbase = Bt + (n0 + srow) * K + sslot * 8;
  #pragma unroll 1
  for (int kt = 0; kt < K; kt += 64){
    #pragma unroll
    for (int ii = 0; ii < 4; ii++){
      int i = w * 4 + ii;
      gl_lds16(Abase + i * 8 * K + kt, sA + i * 512);
      gl_lds16(Bbase + i * 8 * K + kt, sB + i * 512);
    }
    __syncthreads();
    #pragma unroll
    for (int kk = 0; kk < 2; kk++){
      s8v af[4], bfr[4];
      #pragma unroll
      for (int mi = 0; mi < 4; mi++){
        int r = (wr << 6) + (mi << 4) + c;
        int slot = ((kk << 2) + g) ^ (r & 7);
        af[mi] = *(const s8v*)(sA + r * 64 + slot * 8);
      }
      #pragma unroll
      for (int ni = 0; ni < 4; ni++){
        int r = (wc << 6) + (ni << 4) + c;
        int slot = ((kk << 2) + g) ^ (r & 7);
        bfr[ni] = *(const s8v*)(sB + r * 64 + slot * 8);
      }
      #pragma unroll
      for (int mi = 0; mi < 4; mi++)
        #pragma unroll
        for (int ni = 0; ni < 4; ni++)
          acc[mi][ni] = mfma16(af[mi], bfr[ni], acc[mi][ni]);
    }
    __syncthreads();
  }
  #pragma unroll
  for (int mi = 0; mi < 4; mi++){
    #pragma unroll
    for (int ni = 0; ni < 4; ni++){
      #pragma unroll
      for (int r = 0; r < 4; r++){
        int m = m0 + (wr << 6) + (mi << 4) + (g << 2) + r;
        int n = n0 + (wc << 6) + (ni << 4) + c;
        if (OUTF32) ((float*)Cv)[m * N + n] = acc[mi][ni][r];
        else        ((u16*)Cv)[m * N + n] = f2bf(acc[mi][ni][r]);
      }
    }
  }
}

// ---------------- RMSNorm + RoPE; Q -> stride 96 (zeros 72..95, xlog2e), K -> stride 128 (zeros 72..127) ----------------
__global__ __launch_bounds__(192) void k_normrope(const u16* __restrict__ Y, const float* __restrict__ cosp,
      const float* __restrict__ sinp, const float* __restrict__ qnw, const float* __restrict__ knw,
      u16* __restrict__ Qp, u16* __restrict__ Kp){
  __shared__ float ly[1728];
  int token = blockIdx.x;
  int t = threadIdx.x, head = t >> 3, j = t & 7;
  int base = head * 72 + j * 9;
  const u16* yr = Y + token * 2304;
  float x[9]; float ss = 0.f;
  #pragma unroll
  for (int i = 0; i < 9; i++){ x[i] = bf2f(yr[base + i]); ss += x[i] * x[i]; }
  ss += __shfl_xor(ss, 1); ss += __shfl_xor(ss, 2); ss += __shfl_xor(ss, 4);
  float inv = rsqrtf(ss * (1.f / 72.f) + 1e-6f);
  const float* wn = (head < 16) ? qnw : knw;
  #pragma unroll
  for (int i = 0; i < 9; i++){ int d = j * 9 + i; ly[base + i] = x[i] * inv * (1.f + wn[d]); }
  __syncthreads();
  const float* cs = cosp + token * 72;
  const float* sn = sinp + token * 72;
  float scale = (head < 16) ? 1.4426950408889634f : 1.0f;
  float o[9];
  #pragma unroll
  for (int i = 0; i < 9; i++){
    int d = j * 9 + i;
    int dm = (d >= 36) ? d - 36 : d;
    float rot = (dm < 18) ? -ly[head * 72 + d + 18] : ly[head * 72 + d - 18];
    o[i] = (ly[base + i] * cs[d] + rot * sn[d]) * scale;
  }
  int b = token >> 11, s = token & 2047;
  if (head < 16){
    u16* dst = Qp + (size_t)(((b << 4) + head) * 2048 + s) * 96;
    #pragma unroll
    for (int i = 0; i < 9; i++) dst[j * 9 + i] = f2bf(o[i]);
    #pragma unroll
    for (int p2 = 0; p2 < 3; p2++) dst[72 + j * 3 + p2] = 0;
  } else {
    u16* dst = Kp + (size_t)(((b << 3) + (head - 16)) * 2048 + s) * 128;
    #pragma unroll
    for (int i = 0; i < 9; i++) dst[j * 9 + i] = f2bf(o[i]);
    #pragma unroll
    for (int p2 = 0; p2 < 7; p2++) dst[72 + j * 7 + p2] = 0;
  }
}

// ---------------- V: RMSNorm (no scale) + transpose -> Vt [4][8][72][2048] ----------------
__global__ __launch_bounds__(256) void k_vtrans(const u16* __restrict__ Y, u16* __restrict__ Vt){
  __shared__ float lv[72][33];
  int st = blockIdx.x, bk = blockIdx.y;
  int b = bk >> 3, kvh = bk & 7;
  int t = threadIdx.x, tl = t >> 3, j = t & 7;
  int token = (b << 11) + (st << 5) + tl;
  const u16* yr = Y + token * 2304 + 1728 + kvh * 72 + j * 9;
  float x[9]; float ss = 0.f;
  #pragma unroll
  for (int i = 0; i < 9; i++){ x[i] = bf2f(yr[i]); ss += x[i] * x[i]; }
  ss += __shfl_xor(ss, 1); ss += __shfl_xor(ss, 2); ss += __shfl_xor(ss, 4);
  float inv = rsqrtf(ss * (1.f / 72.f) + 1e-6f);
  #pragma unroll
  for (int i = 0; i < 9; i++) lv[j * 9 + i][tl] = x[i] * inv;
  __syncthreads();
  u16* vb = Vt + bk * 72 * 2048 + (st << 5);
  for (int e = t; e < 72 * 32; e += 256){
    int r = e >> 5, cl = e & 31;
    vb[r * 2048 + cl] = f2bf(lv[r][cl]);
  }
}

// ---------------- Flash attention: 32x32x16, KT=128, 64 q/wave, half-split softmax ----------------
// grid (64 bh, 4 qt). 8 waves x 64 q-rows (2 q-tiles of 32). 256 blocks = 1/CU.
__global__ __launch_bounds__(512, 2) void k_attn(const u16* __restrict__ Qp, const u16* __restrict__ Kp,
                                                 const u16* __restrict__ Vt, u16* __restrict__ O){
  __shared__ u16 sK[2][128 * 128];  // [buf][key][16 slots of 8]; phys slot = s ^ (key&15)   64KB
  __shared__ u16 sV[2][96 * 128];   // [buf][d][16 slots of 8]; phys = s ^ (d&15); d>=72 garbage  48KB
  int tid = threadIdx.x, w = tid >> 6, lane = tid & 63, hi = lane >> 5, l31 = lane & 31;
  int bh = blockIdx.x, qt = blockIdx.y;
  int b = bh >> 4, h = bh & 15, kv = h >> 1, bk = (b << 3) + kv;
  int q0 = (qt << 9) + (w << 6) + l31;          // q-tile A; q-tile B = q0 + 32
  const u16* qbase = Qp + (size_t)(((b << 4) + h) << 11) * 96;
  s8v qfa[5], qfb[5];
  #pragma unroll
  for (int ds = 0; ds < 5; ds++){
    qfa[ds] = *(const s8v*)(qbase + (size_t)q0 * 96 + ds * 16 + hi * 8);
    qfb[ds] = *(const s8v*)(qbase + (size_t)(q0 + 32) * 96 + ds * 16 + hi * 8);
  }
  f32x16 aoa[3] = {}, aob[3] = {};
  float mva = -3.0e38f, lspa = 0.f, mvb = -3.0e38f, lspb = 0.f;
  const char* kb = (const char*)Kp + (size_t)bk * 2048 * 256;
  const char* vb = (const char*)Vt + (size_t)bk * 72 * 4096;
  // t-invariant LDS read bases; XOR slot swizzle and hi folded in at setup.
  int rr = l31 & 15;
  const u16* kptr[5];
  #pragma unroll
  for (int ds = 0; ds < 5; ds++)
    kptr[ds] = &sK[0][0] + l31 * 128 + (((ds * 2 + hi) ^ rr) << 3);
  const u16* vptr[8];     // indexed by sbase/2: s = sbase + hi, sbase even in 0..14
  #pragma unroll
  for (int sb2 = 0; sb2 < 8; sb2++)
    vptr[sb2] = &sV[0][0] + l31 * 128 + ((((sb2 * 2) + hi) ^ rr) << 3);
  // K staging: 2048 chunks of 16B; wave w takes n = (i*8+w)*64+lane, i=0..3
  int ko[4], kd[4];
  #pragma unroll
  for (int i = 0; i < 4; i++){
    int n = (i * 8 + w) * 64 + lane;
    int kr = n >> 4, sp = n & 15;
    ko[i] = kr * 256 + ((sp ^ (kr & 15)) << 4);
    kd[i] = n << 4;
  }
  // V staging: 1152 chunks
  int vo[3], vd[3];
  #pragma unroll
  for (int i = 0; i < 3; i++){
    int n = (i < 2) ? (i * 512 + w * 64 + lane) : (1024 + w * 16 + (lane & 15));
    int vr = n >> 4, sp = n & 15;
    vo[i] = vr * 4096 + ((sp ^ (vr & 15)) << 4);
    vd[i] = n << 4;
  }

#define STAGE(buf, t1) { \
    const char* kt_ = kb + (size_t)(t1) * 32768; \
    gl_lds16(kt_ + ko[0], (char*)sK[buf] + kd[0]); \
    gl_lds16(kt_ + ko[1], (char*)sK[buf] + kd[1]); \
    gl_lds16(kt_ + ko[2], (char*)sK[buf] + kd[2]); \
    gl_lds16(kt_ + ko[3], (char*)sK[buf] + kd[3]); \
    const char* vt_ = vb + (size_t)(t1) * 256; \
    gl_lds16(vt_ + vo[0], (char*)sV[buf] + vd[0]); \
    gl_lds16(vt_ + vo[1], (char*)sV[buf] + vd[1]); \
    if (lane < 16) gl_lds16(vt_ + vo[2], (char*)sV[buf] + vd[2]); }

#define MK_PF(S, mlo, PF) { \
      u32 a0 = cvtpk(S[mlo + 0], S[mlo + 1]); \
      u32 a1 = cvtpk(S[mlo + 2], S[mlo + 3]); \
      u32 b0 = cvtpk(S[mlo + 4], S[mlo + 5]); \
      u32 b1 = cvtpk(S[mlo + 6], S[mlo + 7]); \
      asm("v_permlane32_swap_b32 %0, %1" : "+v"(a0), "+v"(b0)); \
      asm("v_permlane32_swap_b32 %0, %1" : "+v"(a1), "+v"(b1)); \
      u32x4 w4 = {a0, a1, b0, b1}; \
      PF = __builtin_bit_cast(s8v, w4); }

  STAGE(0, 0)
  __syncthreads();

  #pragma unroll 2
  for (int t = 0; t < 16; t++){
    int cur = t & 1, nxt = cur ^ 1;
    if (t < 15){ STAGE(nxt, t + 1) }
    #pragma unroll
    for (int hf = 0; hf < 2; hf++){
      // ---- QK^T half: 2 key-subtiles x 2 q-tiles (K frag shared) ----
      f32x16 sa0 = {}, sa1 = {}, sb0 = {}, sb1 = {};
      __builtin_amdgcn_s_setprio(1);
      #pragma unroll
      for (int ds = 0; ds < 5; ds++){
        s8v kf0 = *(const s8v*)(kptr[ds] + cur * 16384 + (hf * 2 + 0) * 4096);
        s8v kf1 = *(const s8v*)(kptr[ds] + cur * 16384 + (hf * 2 + 1) * 4096);
        sa0 = mfma32(kf0, qfa[ds], sa0);
        sb0 = mfma32(kf0, qfb[ds], sb0);
        sa1 = mfma32(kf1, qfa[ds], sa1);
        sb1 = mfma32(kf1, qfb[ds], sb1);
      }
      __builtin_amdgcn_s_setprio(0);
      // ---- online softmax (exp2 domain), per q-tile ----
      float tma = sa0[0], tmb = sb0[0];
      #pragma unroll
      for (int i = 0; i < 16; i++){
        tma = fmaxf(tma, fmaxf(sa0[i], sa1[i]));
        tmb = fmaxf(tmb, fmaxf(sb0[i], sb1[i]));
      }
      tma = fmaxf(tma, __shfl_xor(tma, 32));
      tmb = fmaxf(tmb, __shfl_xor(tmb, 32));
      if (!__all(tma <= mva + 8.f && tmb <= mvb + 8.f)){
        float mna = fmaxf(mva, tma), mnb = fmaxf(mvb, tmb);
        float sca = exp2f(mva - mna), scb = exp2f(mvb - mnb);
        lspa *= sca; lspb *= scb;
        aoa[0] *= sca; aoa[1] *= sca; aoa[2] *= sca;
        aob[0] *= scb; aob[1] *= scb; aob[2] *= scb;
        mva = mna; mvb = mnb;
      }
      float tsa = 0.f, tsb = 0.f;
      #pragma unroll
      for (int i = 0; i < 16; i++){
        float ea0 = exp2f(sa0[i] - mva); sa0[i] = ea0;
        float ea1 = exp2f(sa1[i] - mva); sa1[i] = ea1;
        tsa += ea0 + ea1;
        float eb0 = exp2f(sb0[i] - mvb); sb0[i] = eb0;
        float eb1 = exp2f(sb1[i] - mvb); sb1[i] = eb1;
        tsb += eb0 + eb1;
      }
      lspa += tsa; lspb += tsb;
      // ---- P -> bf16 B-frags in-register ----
      s8v pa0, pa1, pa2, pa3, pb0, pb1, pb2, pb3;
      MK_PF(sa0, 0, pa0) MK_PF(sa0, 8, pa1) MK_PF(sa1, 0, pa2) MK_PF(sa1, 8, pa3)
      MK_PF(sb0, 0, pb0) MK_PF(sb0, 8, pb1) MK_PF(sb1, 0, pb2) MK_PF(sb1, 8, pb3)
      // ---- PV: V frag shared by both q-tiles; vptr index = (hf*8 + j2*4 + k*2)/2 ----
      __builtin_amdgcn_s_setprio(1);
      #pragma unroll
      for (int dt = 0; dt < 3; dt++){
        s8v vf00 = *(const s8v*)(vptr[hf * 4 + 0] + cur * 12288 + dt * 4096);
        s8v vf01 = *(const s8v*)(vptr[hf * 4 + 1] + cur * 12288 + dt * 4096);
        s8v vf10 = *(const s8v*)(vptr[hf * 4 + 2] + cur * 12288 + dt * 4096);
        s8v vf11 = *(const s8v*)(vptr[hf * 4 + 3] + cur * 12288 + dt * 4096);
        aoa[dt] = mfma32(vf00, pa0, aoa[dt]);
        aob[dt] = mfma32(vf00, pb0, aob[dt]);
        aoa[dt] = mfma32(vf01, pa1, aoa[dt]);
        aob[dt] = mfma32(vf01, pb1, aob[dt]);
        aoa[dt] = mfma32(vf10, pa2, aoa[dt]);
        aob[dt] = mfma32(vf10, pb2, aob[dt]);
        aoa[dt] = mfma32(vf11, pa3, aoa[dt]);
        aob[dt] = mfma32(vf11, pb3, aob[dt]);
      }
      __builtin_amdgcn_s_setprio(0);
    }
    __syncthreads();
  }
  float lsa = lspa + __shfl_xor(lspa, 32);
  float lsb = lspb + __shfl_xor(lspb, 32);
  float inva = 1.f / lsa, invb = 1.f / lsb;
  u16* oba = O + (size_t)((((b << 11) + q0) << 4) + h) * 72;
  u16* obb = O + (size_t)((((b << 11) + q0 + 32) << 4) + h) * 72;
  #pragma unroll
  for (int dt = 0; dt < 3; dt++){
    #pragma unroll
    for (int gp = 0; gp < 4; gp++){
      int d = dt * 32 + gp * 8 + hi * 4;
      if (d < 72){
        u32x2 o2;
        o2.x = cvtpk(aoa[dt][gp * 4 + 0] * inva, aoa[dt][gp * 4 + 1] * inva);
        o2.y = cvtpk(aoa[dt][gp * 4 + 2] * inva, aoa[dt][gp * 4 + 3] * inva);
        *(u32x2*)(oba + d) = o2;
        u32x2 o3;
        o3.x = cvtpk(aob[dt][gp * 4 + 0] * invb, aob[dt][gp * 4 + 1] * invb);
        o3.y = cvtpk(aob[dt][gp * 4 + 2] * invb, aob[dt][gp * 4 + 3] * invb);
        *(u32x2*)(obb + d) = o3;
      }
    }
  }
#undef STAGE
#undef MK_PF
}

// ---------------- launch ----------------
extern "C" void kernel_launch(void* const* d_in, const int* in_sizes, int n_in,
                              void* d_out, int out_size, void* d_ws, size_t ws_size,
                              hipStream_t stream){
  (void)in_sizes; (void)n_in; (void)out_size; (void)ws_size;
  const float* hs   = (const float*)d_in[0];
  const float* cosp = (const float*)d_in[1];
  const float* sinp = (const float*)d_in[2];
  const float* Wq   = (const float*)d_in[5];
  const float* Wk   = (const float*)d_in[6];
  const float* Wv   = (const float*)d_in[7];
  const float* Wo   = (const float*)d_in[8];
  const float* qnw  = (const float*)d_in[9];
  const float* knw  = (const float*)d_in[10];
  char* ws = (char*)d_ws;
  u16* Xb    = (u16*)(ws);                    // 18,874,368 B (reused as O after gemm1)
  u16* WtQKV = (u16*)(ws + 18874368);         //  5,308,416 B
  u16* Wot   = (u16*)(ws + 24182784);         //  2,654,208 B
  u16* Y     = (u16*)(ws + 26836992);         // 37,748,736 B
  u16* Qp    = (u16*)(ws + 64585728);         // 25,165,824 B (stride 96)
  u16* Kp    = (u16*)(ws + 89751552);         // 16,777,216 B (stride 128)
  u16* Vt    = (u16*)(ws + 106528768);        //  9,437,184 B  (total 115,965,952)
  u16* O     = Xb;

  k_prepx<<<4608, 256, 0, stream>>>(hs, Xb, 8192 * 1152);
  k_transpose<<<36 * 36, 256, 0, stream>>>(Wq, WtQKV, 1152, 1152, 1152);
  k_transpose<<<36 * 18, 256, 0, stream>>>(Wk, WtQKV + 1152 * 1152, 1152, 576, 1152);
  k_transpose<<<36 * 18, 256, 0, stream>>>(Wv, WtQKV + 1728 * 1152, 1152, 576, 1152);
  k_transpose<<<36 * 36, 256, 0, stream>>>(Wo, Wot, 1152, 1152, 1152);
  k_gemm<0><<<dim3(18, 64), 256, 0, stream>>>(Xb, WtQKV, Y, 8192, 2304, 1152);
  k_normrope<<<8192, 192, 0, stream>>>(Y, cosp, sinp, qnw, knw, Qp, Kp);
  k_vtrans<<<dim3(64, 32), 256, 0, stream>>>(Y, Vt);
  k_attn<<<dim3(64, 4), 512, 0, stream>>>(Qp, Kp, Vt, O);
  k_gemm<1><<<dim3(9, 64), 256, 0, stream>>>(O, Wot, (float*)d_out, 8192, 1152, 1152);
}

// Round 10
// 327.293 us; speedup vs baseline: 1.0447x; 1.0447x over previous
//
#include <hip/hip_runtime.h>

typedef unsigned int u32;
typedef unsigned short u16;
typedef __attribute__((ext_vector_type(8))) short s8v;
typedef __attribute__((ext_vector_type(8))) __bf16 b8v;
typedef __attribute__((ext_vector_type(4))) float f4v;
typedef __attribute__((ext_vector_type(16))) float f32x16;
typedef __attribute__((ext_vector_type(4))) u32 u32x4;
typedef __attribute__((ext_vector_type(2))) u32 u32x2;

#define DEV static __device__ __forceinline__

DEV u32 cvtpk(float a, float b){ u32 r; asm("v_cvt_pk_bf16_f32 %0, %1, %2" : "=v"(r) : "v"(a), "v"(b)); return r; }
DEV u16 f2bf(float x){ return (u16)(cvtpk(x, x) & 0xffffu); }
DEV float bf2f(u16 u){ return __builtin_bit_cast(float, ((u32)u) << 16); }

DEV f4v mfma16(s8v a, s8v b, f4v c){
  return __builtin_amdgcn_mfma_f32_16x16x32_bf16(__builtin_bit_cast(b8v, a), __builtin_bit_cast(b8v, b), c, 0, 0, 0);
}
DEV f32x16 mfma32(s8v a, s8v b, f32x16 c){
  return __builtin_amdgcn_mfma_f32_32x32x16_bf16(__builtin_bit_cast(b8v, a), __builtin_bit_cast(b8v, b), c, 0, 0, 0);
}

DEV void gl_lds16(const void* g, void* l){
  __builtin_amdgcn_global_load_lds((const __attribute__((address_space(1))) u32*)g,
                                   (__attribute__((address_space(3))) u32*)l, 16, 0, 0);
}

// ---------------- prep: X fp32 -> bf16 ----------------
__global__ __launch_bounds__(256) void k_prepx(const float* __restrict__ x, u16* __restrict__ xb, int n){
  int i = (blockIdx.x * 256 + threadIdx.x) * 8;
  if (i >= n) return;
  float4 a = *(const float4*)(x + i);
  float4 b = *(const float4*)(x + i + 4);
  u32x4 o;
  o.x = cvtpk(a.x, a.y); o.y = cvtpk(a.z, a.w);
  o.z = cvtpk(b.x, b.y); o.w = cvtpk(b.z, b.w);
  *(u32x4*)(xb + i) = o;
}

// ---------------- prep: transpose fp32 [K][N] -> bf16 [N][K] (ldd) ----------------
__global__ __launch_bounds__(256) void k_transpose(const float* __restrict__ src, u16* __restrict__ dst,
                                                   int K, int N, int ldd){
  __shared__ float t[32][33];
  int nt = N >> 5;
  int k0 = (blockIdx.x / nt) << 5, n0 = (blockIdx.x % nt) << 5;
  int col = threadIdx.x & 31, rw = threadIdx.x >> 5;
  #pragma unroll
  for (int i = 0; i < 4; i++){ int r = rw + i * 8; t[r][col] = src[(k0 + r) * N + n0 + col]; }
  __syncthreads();
  #pragma unroll
  for (int i = 0; i < 4; i++){ int r = rw + i * 8; dst[(n0 + r) * ldd + k0 + col] = f2bf(t[col][r]); }
}

// ---------------- GEMM: C[M,N] = A[M,K] * Bt[N,K]^T, bf16 in, bf16 or f32 out ----------------
template<int OUTF32>
__global__ __launch_bounds__(256) void k_gemm(const u16* __restrict__ A, const u16* __restrict__ Bt,
                                              void* __restrict__ Cv, int M, int N, int K){
  __shared__ u16 sA[128 * 64];
  __shared__ u16 sB[128 * 64];
  int tid = threadIdx.x, w = tid >> 6, lane = tid & 63, g = lane >> 4, c = lane & 15;
  int n0 = blockIdx.x << 7, m0 = blockIdx.y << 7;
  int wr = w >> 1, wc = w & 1;
  f4v acc[4][4] = {};
  int srow = lane >> 3;
  int sslot = (lane & 7) ^ srow;
  const u16* Abase = A + (m0 + srow) * K + sslot * 8;
  const u16* Bbase = Bt + (n0 + srow) * K + sslot * 8;
  #pragma unroll 1
  for (int kt = 0; kt < K; kt += 64){
    #pragma unroll
    for (int ii = 0; ii < 4; ii++){
      int i = w * 4 + ii;
      gl_lds16(Abase + i * 8 * K + kt, sA + i * 512);
      gl_lds16(Bbase + i * 8 * K + kt, sB + i * 512);
    }
    __syncthreads();
    #pragma unroll
    for (int kk = 0; kk < 2; kk++){
      s8v af[4], bfr[4];
      #pragma unroll
      for (int mi = 0; mi < 4; mi++){
        int r = (wr << 6) + (mi << 4) + c;
        int slot = ((kk << 2) + g) ^ (r & 7);
        af[mi] = *(const s8v*)(sA + r * 64 + slot * 8);
      }
      #pragma unroll
      for (int ni = 0; ni < 4; ni++){
        int r = (wc << 6) + (ni << 4) + c;
        int slot = ((kk << 2) + g) ^ (r & 7);
        bfr[ni] = *(const s8v*)(sB + r * 64 + slot * 8);
      }
      #pragma unroll
      for (int mi = 0; mi < 4; mi++)
        #pragma unroll
        for (int ni = 0; ni < 4; ni++)
          acc[mi][ni] = mfma16(af[mi], bfr[ni], acc[mi][ni]);
    }
    __syncthreads();
  }
  #pragma unroll
  for (int mi = 0; mi < 4; mi++){
    #pragma unroll
    for (int ni = 0; ni < 4; ni++){
      #pragma unroll
      for (int r = 0; r < 4; r++){
        int m = m0 + (wr << 6) + (mi << 4) + (g << 2) + r;
        int n = n0 + (wc << 6) + (ni << 4) + c;
        if (OUTF32) ((float*)Cv)[m * N + n] = acc[mi][ni][r];
        else        ((u16*)Cv)[m * N + n] = f2bf(acc[mi][ni][r]);
      }
    }
  }
}

// ---------------- RMSNorm + RoPE; Q -> stride 96 (zeros 72..95, xlog2e), K -> stride 128 (zeros 72..127) ----------------
__global__ __launch_bounds__(192) void k_normrope(const u16* __restrict__ Y, const float* __restrict__ cosp,
      const float* __restrict__ sinp, const float* __restrict__ qnw, const float* __restrict__ knw,
      u16* __restrict__ Qp, u16* __restrict__ Kp){
  __shared__ float ly[1728];
  int token = blockIdx.x;
  int t = threadIdx.x, head = t >> 3, j = t & 7;
  int base = head * 72 + j * 9;
  const u16* yr = Y + token * 2304;
  float x[9]; float ss = 0.f;
  #pragma unroll
  for (int i = 0; i < 9; i++){ x[i] = bf2f(yr[base + i]); ss += x[i] * x[i]; }
  ss += __shfl_xor(ss, 1); ss += __shfl_xor(ss, 2); ss += __shfl_xor(ss, 4);
  float inv = rsqrtf(ss * (1.f / 72.f) + 1e-6f);
  const float* wn = (head < 16) ? qnw : knw;
  #pragma unroll
  for (int i = 0; i < 9; i++){ int d = j * 9 + i; ly[base + i] = x[i] * inv * (1.f + wn[d]); }
  __syncthreads();
  const float* cs = cosp + token * 72;
  const float* sn = sinp + token * 72;
  float scale = (head < 16) ? 1.4426950408889634f : 1.0f;
  float o[9];
  #pragma unroll
  for (int i = 0; i < 9; i++){
    int d = j * 9 + i;
    int dm = (d >= 36) ? d - 36 : d;
    float rot = (dm < 18) ? -ly[head * 72 + d + 18] : ly[head * 72 + d - 18];
    o[i] = (ly[base + i] * cs[d] + rot * sn[d]) * scale;
  }
  int b = token >> 11, s = token & 2047;
  if (head < 16){
    u16* dst = Qp + (size_t)(((b << 4) + head) * 2048 + s) * 96;
    #pragma unroll
    for (int i = 0; i < 9; i++) dst[j * 9 + i] = f2bf(o[i]);
    #pragma unroll
    for (int p2 = 0; p2 < 3; p2++) dst[72 + j * 3 + p2] = 0;
  } else {
    u16* dst = Kp + (size_t)(((b << 3) + (head - 16)) * 2048 + s) * 128;
    #pragma unroll
    for (int i = 0; i < 9; i++) dst[j * 9 + i] = f2bf(o[i]);
    #pragma unroll
    for (int p2 = 0; p2 < 7; p2++) dst[72 + j * 7 + p2] = 0;
  }
}

// ---------------- V: RMSNorm (no scale) + transpose -> Vt [4][8][72][2048] ----------------
__global__ __launch_bounds__(256) void k_vtrans(const u16* __restrict__ Y, u16* __restrict__ Vt){
  __shared__ float lv[72][33];
  int st = blockIdx.x, bk = blockIdx.y;
  int b = bk >> 3, kvh = bk & 7;
  int t = threadIdx.x, tl = t >> 3, j = t & 7;
  int token = (b << 11) + (st << 5) + tl;
  const u16* yr = Y + token * 2304 + 1728 + kvh * 72 + j * 9;
  float x[9]; float ss = 0.f;
  #pragma unroll
  for (int i = 0; i < 9; i++){ x[i] = bf2f(yr[i]); ss += x[i] * x[i]; }
  ss += __shfl_xor(ss, 1); ss += __shfl_xor(ss, 2); ss += __shfl_xor(ss, 4);
  float inv = rsqrtf(ss * (1.f / 72.f) + 1e-6f);
  #pragma unroll
  for (int i = 0; i < 9; i++) lv[j * 9 + i][tl] = x[i] * inv;
  __syncthreads();
  u16* vb = Vt + bk * 72 * 2048 + (st << 5);
  for (int e = t; e < 72 * 32; e += 256){
    int r = e >> 5, cl = e & 31;
    vb[r * 2048 + cl] = f2bf(lv[r][cl]);
  }
}

// ---------------- Flash attention: 32x32x16, KT=128, GQA head-pairing, per-subtile pipeline ----------------
// grid (32 bk, 16 qtiles of 128). 8 waves: w<4 -> head 2kv, w>=4 -> head 2kv+1; 32 q-rows/wave.
// Per 32-key subtile: QK -> softmax -> PV, so only 16 score floats are live at a time.
// Cross-half exchanges use __shfl_xor(.,32) (validated R1-R5); degenerate permlane32_swap is BROKEN (R7-R9).
__global__ __launch_bounds__(512, 2) void k_attn(const u16* __restrict__ Qp, const u16* __restrict__ Kp,
                                                 const u16* __restrict__ Vt, u16* __restrict__ O){
  __shared__ u16 sK[2][128 * 128];  // [buf][key][16 slots of 8]; phys slot = s ^ (key&15)   64KB
  __shared__ u16 sV[2][96 * 128];   // [buf][d][16 slots of 8]; phys = s ^ (d&15); d>=72 garbage  48KB
  int tid = threadIdx.x, w = tid >> 6, lane = tid & 63, hi = lane >> 5, l31 = lane & 31;
  int bk = blockIdx.x, qt = blockIdx.y;     // all 16 qt-blocks of bk land on XCD bk&7
  int b = bk >> 3, kv = bk & 7;
  int h = (kv << 1) + (w >> 2);
  int q = (qt << 7) + ((w & 3) << 5) + l31;
  const u16* qb = Qp + (size_t)((((b << 4) + h) << 11) + q) * 96;
  s8v qf[5];
  #pragma unroll
  for (int ds = 0; ds < 5; ds++) qf[ds] = *(const s8v*)(qb + ds * 16 + hi * 8);
  f32x16 ao[3] = {};
  float mv = -3.0e38f, lsp = 0.f;
  const char* kb = (const char*)Kp + (size_t)bk * 2048 * 256;
  const char* vb = (const char*)Vt + (size_t)bk * 72 * 4096;
  // K staging: 2048 chunks of 16B; wave w takes n = (i*8+w)*64+lane, i=0..3
  int ko[4], kd[4];
  #pragma unroll
  for (int i = 0; i < 4; i++){
    int n = (i * 8 + w) * 64 + lane;
    int kr = n >> 4, sp = n & 15;
    ko[i] = kr * 256 + ((sp ^ (kr & 15)) << 4);
    kd[i] = n << 4;
  }
  // V staging: 1152 chunks (72 rows x 16); batches n, 512+n, 1024+w*16+(lane&15)
  int vo[3], vd[3];
  #pragma unroll
  for (int i = 0; i < 3; i++){
    int n = (i < 2) ? (i * 512 + w * 64 + lane) : (1024 + w * 16 + (lane & 15));
    int vr = n >> 4, sp = n & 15;
    vo[i] = vr * 4096 + ((sp ^ (vr & 15)) << 4);
    vd[i] = n << 4;
  }

#define STAGE(buf, t1) { \
    const char* kt_ = kb + (size_t)(t1) * 32768; \
    gl_lds16(kt_ + ko[0], (char*)sK[buf] + kd[0]); \
    gl_lds16(kt_ + ko[1], (char*)sK[buf] + kd[1]); \
    gl_lds16(kt_ + ko[2], (char*)sK[buf] + kd[2]); \
    gl_lds16(kt_ + ko[3], (char*)sK[buf] + kd[3]); \
    const char* vt_ = vb + (size_t)(t1) * 256; \
    gl_lds16(vt_ + vo[0], (char*)sV[buf] + vd[0]); \
    gl_lds16(vt_ + vo[1], (char*)sV[buf] + vd[1]); \
    if (lane < 16) gl_lds16(vt_ + vo[2], (char*)sV[buf] + vd[2]); }

#define MK_PF(S, mlo, PF) { \
      u32 a0 = cvtpk(S[mlo + 0], S[mlo + 1]); \
      u32 a1 = cvtpk(S[mlo + 2], S[mlo + 3]); \
      u32 b0 = cvtpk(S[mlo + 4], S[mlo + 5]); \
      u32 b1 = cvtpk(S[mlo + 6], S[mlo + 7]); \
      asm("v_permlane32_swap_b32 %0, %1" : "+v"(a0), "+v"(b0)); \
      asm("v_permlane32_swap_b32 %0, %1" : "+v"(a1), "+v"(b1)); \
      u32x4 w4 = {a0, a1, b0, b1}; \
      PF = __builtin_bit_cast(s8v, w4); }

  STAGE(0, 0)
  __syncthreads();

  #pragma unroll 1
  for (int t = 0; t < 16; t++){
    int cur = t & 1, nxt = cur ^ 1;
    if (t < 15){ STAGE(nxt, t + 1) }
    const u16* sKc = sK[cur];
    const u16* sVc = sV[cur];
    #pragma unroll
    for (int j = 0; j < 4; j++){
      // ---- QK^T subtile j: C[key][q], keys j*32..j*32+31 ----
      f32x16 sc = {};
      int r = j * 32 + l31;
      __builtin_amdgcn_s_setprio(1);
      #pragma unroll
      for (int ds = 0; ds < 5; ds++){
        int s = ds * 2 + hi;
        s8v kf = *(const s8v*)(sKc + r * 128 + ((s ^ (r & 15)) << 3));
        sc = mfma32(kf, qf[ds], sc);
      }
      __builtin_amdgcn_s_setprio(0);
      // ---- online softmax (exp2 domain): 16 scores/lane, tree reductions ----
      float t8[8];
      #pragma unroll
      for (int i = 0; i < 8; i++) t8[i] = fmaxf(sc[i], sc[i + 8]);
      #pragma unroll
      for (int i = 0; i < 4; i++) t8[i] = fmaxf(t8[i], t8[i + 4]);
      float tm = fmaxf(fmaxf(t8[0], t8[1]), fmaxf(t8[2], t8[3]));
      tm = fmaxf(tm, __shfl_xor(tm, 32));
      if (!__all(tm <= mv + 8.f)){
        float mn = fmaxf(mv, tm);
        float scl = exp2f(mv - mn);
        lsp *= scl;
        ao[0] *= scl; ao[1] *= scl; ao[2] *= scl;
        mv = mn;
      }
      float ps[8];
      #pragma unroll
      for (int i = 0; i < 8; i++){
        float e0 = exp2f(sc[i] - mv);
        float e1 = exp2f(sc[i + 8] - mv);
        sc[i] = e0; sc[i + 8] = e1;
        ps[i] = e0 + e1;
      }
      #pragma unroll
      for (int i = 0; i < 4; i++) ps[i] += ps[i + 4];
      lsp += (ps[0] + ps[1]) + (ps[2] + ps[3]);
      // ---- P -> bf16 B-frags in-register ----
      s8v pfa, pfb;
      MK_PF(sc, 0, pfa)
      MK_PF(sc, 8, pfb)
      // ---- PV subtile j ----
      __builtin_amdgcn_s_setprio(1);
      #pragma unroll
      for (int dt = 0; dt < 3; dt++){
        int rv = dt * 32 + l31;
        int s0 = 4 * j + hi, s1 = 4 * j + 2 + hi;
        s8v vf0 = *(const s8v*)(sVc + rv * 128 + ((s0 ^ (rv & 15)) << 3));
        s8v vf1 = *(const s8v*)(sVc + rv * 128 + ((s1 ^ (rv & 15)) << 3));
        ao[dt] = mfma32(vf0, pfa, ao[dt]);
        ao[dt] = mfma32(vf1, pfb, ao[dt]);
      }
      __builtin_amdgcn_s_setprio(0);
    }
    __syncthreads();
  }
  float ls = lsp + __shfl_xor(lsp, 32);
  float inv = 1.f / ls;
  u16* ob = O + (size_t)((((b << 11) + q) << 4) + h) * 72;
  #pragma unroll
  for (int dt = 0; dt < 3; dt++){
    #pragma unroll
    for (int gp = 0; gp < 4; gp++){
      int d = dt * 32 + gp * 8 + hi * 4;
      if (d < 72){
        u32x2 o2;
        o2.x = cvtpk(ao[dt][gp * 4 + 0] * inv, ao[dt][gp * 4 + 1] * inv);
        o2.y = cvtpk(ao[dt][gp * 4 + 2] * inv, ao[dt][gp * 4 + 3] * inv);
        *(u32x2*)(ob + d) = o2;
      }
    }
  }
#undef STAGE
#undef MK_PF
}

// ---------------- launch ----------------
extern "C" void kernel_launch(void* const* d_in, const int* in_sizes, int n_in,
                              void* d_out, int out_size, void* d_ws, size_t ws_size,
                              hipStream_t stream){
  (void)in_sizes; (void)n_in; (void)out_size; (void)ws_size;
  const float* hs   = (const float*)d_in[0];
  const float* cosp = (const float*)d_in[1];
  const float* sinp = (const float*)d_in[2];
  const float* Wq   = (const float*)d_in[5];
  const float* Wk   = (const float*)d_in[6];
  const float* Wv   = (const float*)d_in[7];
  const float* Wo   = (const float*)d_in[8];
  const float* qnw  = (const float*)d_in[9];
  const float* knw  = (const float*)d_in[10];
  char* ws = (char*)d_ws;
  u16* Xb    = (u16*)(ws);                    // 18,874,368 B (reused as O after gemm1)
  u16* WtQKV = (u16*)(ws + 18874368);         //  5,308,416 B
  u16* Wot   = (u16*)(ws + 24182784);         //  2,654,208 B
  u16* Y     = (u16*)(ws + 26836992);         // 37,748,736 B
  u16* Qp    = (u16*)(ws + 64585728);         // 25,165,824 B (stride 96)
  u16* Kp    = (u16*)(ws + 89751552);         // 16,777,216 B (stride 128)
  u16* Vt    = (u16*)(ws + 106528768);        //  9,437,184 B  (total 115,965,952)
  u16* O     = Xb;

  k_prepx<<<4608, 256, 0, stream>>>(hs, Xb, 8192 * 1152);
  k_transpose<<<36 * 36, 256, 0, stream>>>(Wq, WtQKV, 1152, 1152, 1152);
  k_transpose<<<36 * 18, 256, 0, stream>>>(Wk, WtQKV + 1152 * 1152, 1152, 576, 1152);
  k_transpose<<<36 * 18, 256, 0, stream>>>(Wv, WtQKV + 1728 * 1152, 1152, 576, 1152);
  k_transpose<<<36 * 36, 256, 0, stream>>>(Wo, Wot, 1152, 1152, 1152);
  k_gemm<0><<<dim3(18, 64), 256, 0, stream>>>(Xb, WtQKV, Y, 8192, 2304, 1152);
  k_normrope<<<8192, 192, 0, stream>>>(Y, cosp, sinp, qnw, knw, Qp, Kp);
  k_vtrans<<<dim3(64, 32), 256, 0, stream>>>(Y, Vt);
  k_attn<<<dim3(32, 16), 512, 0, stream>>>(Qp, Kp, Vt, O);
  k_gemm<1><<<dim3(9, 64), 256, 0, stream>>>(O, Wot, (float*)d_out, 8192, 1152, 1152);
}

// Round 11
// 283.462 us; speedup vs baseline: 1.2063x; 1.1546x over previous
//
#include <hip/hip_runtime.h>

typedef unsigned int u32;
typedef unsigned short u16;
typedef __attribute__((ext_vector_type(8))) short s8v;
typedef __attribute__((ext_vector_type(8))) __bf16 b8v;
typedef __attribute__((ext_vector_type(4))) float f4v;
typedef __attribute__((ext_vector_type(16))) float f32x16;
typedef __attribute__((ext_vector_type(4))) u32 u32x4;
typedef __attribute__((ext_vector_type(2))) u32 u32x2;

#define DEV static __device__ __forceinline__

DEV u32 cvtpk(float a, float b){ u32 r; asm("v_cvt_pk_bf16_f32 %0, %1, %2" : "=v"(r) : "v"(a), "v"(b)); return r; }
DEV u16 f2bf(float x){ return (u16)(cvtpk(x, x) & 0xffffu); }
DEV float bf2f(u16 u){ return __builtin_bit_cast(float, ((u32)u) << 16); }

DEV f4v mfma16(s8v a, s8v b, f4v c){
  return __builtin_amdgcn_mfma_f32_16x16x32_bf16(__builtin_bit_cast(b8v, a), __builtin_bit_cast(b8v, b), c, 0, 0, 0);
}
DEV f32x16 mfma32(s8v a, s8v b, f32x16 c){
  return __builtin_amdgcn_mfma_f32_32x32x16_bf16(__builtin_bit_cast(b8v, a), __builtin_bit_cast(b8v, b), c, 0, 0, 0);
}

DEV void gl_lds16(const void* g, void* l){
  __builtin_amdgcn_global_load_lds((const __attribute__((address_space(1))) u32*)g,
                                   (__attribute__((address_space(3))) u32*)l, 16, 0, 0);
}

// ---------------- prep: X fp32 -> bf16 ----------------
__global__ __launch_bounds__(256) void k_prepx(const float* __restrict__ x, u16* __restrict__ xb, int n){
  int i = (blockIdx.x * 256 + threadIdx.x) * 8;
  if (i >= n) return;
  float4 a = *(const float4*)(x + i);
  float4 b = *(const float4*)(x + i + 4);
  u32x4 o;
  o.x = cvtpk(a.x, a.y); o.y = cvtpk(a.z, a.w);
  o.z = cvtpk(b.x, b.y); o.w = cvtpk(b.z, b.w);
  *(u32x4*)(xb + i) = o;
}

// ---------------- prep: transpose fp32 [K][N] -> bf16 [N][K] (ldd) ----------------
__global__ __launch_bounds__(256) void k_transpose(const float* __restrict__ src, u16* __restrict__ dst,
                                                   int K, int N, int ldd){
  __shared__ float t[32][33];
  int nt = N >> 5;
  int k0 = (blockIdx.x / nt) << 5, n0 = (blockIdx.x % nt) << 5;
  int col = threadIdx.x & 31, rw = threadIdx.x >> 5;
  #pragma unroll
  for (int i = 0; i < 4; i++){ int r = rw + i * 8; t[r][col] = src[(k0 + r) * N + n0 + col]; }
  __syncthreads();
  #pragma unroll
  for (int i = 0; i < 4; i++){ int r = rw + i * 8; dst[(n0 + r) * ldd + k0 + col] = f2bf(t[col][r]); }
}

// ---------------- GEMM: C[M,N] = A[M,K] * Bt[N,K]^T, bf16 in, bf16 or f32 out ----------------
template<int OUTF32>
__global__ __launch_bounds__(256) void k_gemm(const u16* __restrict__ A, const u16* __restrict__ Bt,
                                              void* __restrict__ Cv, int M, int N, int K){
  __shared__ u16 sA[128 * 64];
  __shared__ u16 sB[128 * 64];
  int tid = threadIdx.x, w = tid >> 6, lane = tid & 63, g = lane >> 4, c = lane & 15;
  int n0 = blockIdx.x << 7, m0 = blockIdx.y << 7;
  int wr = w >> 1, wc = w & 1;
  f4v acc[4][4] = {};
  int srow = lane >> 3;
  int sslot = (lane & 7) ^ srow;
  const u16* Abase = A + (m0 + srow) * K + sslot * 8;
  const u16* Bbase = Bt + (n0 + srow) * K + sslot * 8;
  #pragma unroll 1
  for (int kt = 0; kt < K; kt += 64){
    #pragma unroll
    for (int ii = 0; ii < 4; ii++){
      int i = w * 4 + ii;
      gl_lds16(Abase + i * 8 * K + kt, sA + i * 512);
      gl_lds16(Bbase + i * 8 * K + kt, sB + i * 512);
    }
    __syncthreads();
    #pragma unroll
    for (int kk = 0; kk < 2; kk++){
      s8v af[4], bfr[4];
      #pragma unroll
      for (int mi = 0; mi < 4; mi++){
        int r = (wr << 6) + (mi << 4) + c;
        int slot = ((kk << 2) + g) ^ (r & 7);
        af[mi] = *(const s8v*)(sA + r * 64 + slot * 8);
      }
      #pragma unroll
      for (int ni = 0; ni < 4; ni++){
        int r = (wc << 6) + (ni << 4) + c;
        int slot = ((kk << 2) + g) ^ (r & 7);
        bfr[ni] = *(const s8v*)(sB + r * 64 + slot * 8);
      }
      #pragma unroll
      for (int mi = 0; mi < 4; mi++)
        #pragma unroll
        for (int ni = 0; ni < 4; ni++)
          acc[mi][ni] = mfma16(af[mi], bfr[ni], acc[mi][ni]);
    }
    __syncthreads();
  }
  #pragma unroll
  for (int mi = 0; mi < 4; mi++){
    #pragma unroll
    for (int ni = 0; ni < 4; ni++){
      #pragma unroll
      for (int r = 0; r < 4; r++){
        int m = m0 + (wr << 6) + (mi << 4) + (g << 2) + r;
        int n = n0 + (wc << 6) + (ni << 4) + c;
        if (OUTF32) ((float*)Cv)[m * N + n] = acc[mi][ni][r];
        else        ((u16*)Cv)[m * N + n] = f2bf(acc[mi][ni][r]);
      }
    }
  }
}

// ---------------- RMSNorm + RoPE; Q -> stride 96 (zeros 72..95, xlog2e), K -> stride 128 (zeros 72..127) ----------------
__global__ __launch_bounds__(192) void k_normrope(const u16* __restrict__ Y, const float* __restrict__ cosp,
      const float* __restrict__ sinp, const float* __restrict__ qnw, const float* __restrict__ knw,
      u16* __restrict__ Qp, u16* __restrict__ Kp){
  __shared__ float ly[1728];
  int token = blockIdx.x;
  int t = threadIdx.x, head = t >> 3, j = t & 7;
  int base = head * 72 + j * 9;
  const u16* yr = Y + token * 2304;
  float x[9]; float ss = 0.f;
  #pragma unroll
  for (int i = 0; i < 9; i++){ x[i] = bf2f(yr[base + i]); ss += x[i] * x[i]; }
  ss += __shfl_xor(ss, 1); ss += __shfl_xor(ss, 2); ss += __shfl_xor(ss, 4);
  float inv = rsqrtf(ss * (1.f / 72.f) + 1e-6f);
  const float* wn = (head < 16) ? qnw : knw;
  #pragma unroll
  for (int i = 0; i < 9; i++){ int d = j * 9 + i; ly[base + i] = x[i] * inv * (1.f + wn[d]); }
  __syncthreads();
  const float* cs = cosp + token * 72;
  const float* sn = sinp + token * 72;
  float scale = (head < 16) ? 1.4426950408889634f : 1.0f;
  float o[9];
  #pragma unroll
  for (int i = 0; i < 9; i++){
    int d = j * 9 + i;
    int dm = (d >= 36) ? d - 36 : d;
    float rot = (dm < 18) ? -ly[head * 72 + d + 18] : ly[head * 72 + d - 18];
    o[i] = (ly[base + i] * cs[d] + rot * sn[d]) * scale;
  }
  int b = token >> 11, s = token & 2047;
  if (head < 16){
    u16* dst = Qp + (size_t)(((b << 4) + head) * 2048 + s) * 96;
    #pragma unroll
    for (int i = 0; i < 9; i++) dst[j * 9 + i] = f2bf(o[i]);
    #pragma unroll
    for (int p2 = 0; p2 < 3; p2++) dst[72 + j * 3 + p2] = 0;
  } else {
    u16* dst = Kp + (size_t)(((b << 3) + (head - 16)) * 2048 + s) * 128;
    #pragma unroll
    for (int i = 0; i < 9; i++) dst[j * 9 + i] = f2bf(o[i]);
    #pragma unroll
    for (int p2 = 0; p2 < 7; p2++) dst[72 + j * 7 + p2] = 0;
  }
}

// ---------------- V: RMSNorm (no scale) + transpose -> Vt [4][8][72][2048] ----------------
__global__ __launch_bounds__(256) void k_vtrans(const u16* __restrict__ Y, u16* __restrict__ Vt){
  __shared__ float lv[72][33];
  int st = blockIdx.x, bk = blockIdx.y;
  int b = bk >> 3, kvh = bk & 7;
  int t = threadIdx.x, tl = t >> 3, j = t & 7;
  int token = (b << 11) + (st << 5) + tl;
  const u16* yr = Y + token * 2304 + 1728 + kvh * 72 + j * 9;
  float x[9]; float ss = 0.f;
  #pragma unroll
  for (int i = 0; i < 9; i++){ x[i] = bf2f(yr[i]); ss += x[i] * x[i]; }
  ss += __shfl_xor(ss, 1); ss += __shfl_xor(ss, 2); ss += __shfl_xor(ss, 4);
  float inv = rsqrtf(ss * (1.f / 72.f) + 1e-6f);
  #pragma unroll
  for (int i = 0; i < 9; i++) lv[j * 9 + i][tl] = x[i] * inv;
  __syncthreads();
  u16* vb = Vt + bk * 72 * 2048 + (st << 5);
  for (int e = t; e < 72 * 32; e += 256){
    int r = e >> 5, cl = e & 31;
    vb[r * 2048 + cl] = f2bf(lv[r][cl]);
  }
}

// ---------------- Flash attention: 32x32x16, KT=64, head-pairing, 2 blocks/CU, per-subtile pipeline ----------------
// grid (32 bk, 16 qt) = 512 blocks, all resident (2/CU, 4 waves/SIMD).
// 8 waves: w<4 -> head 2kv, w>=4 -> head 2kv+1; 32 q-rows/wave; 2 key-subtiles of 32 per 64-key tile.
__global__ __launch_bounds__(512, 4) void k_attn(const u16* __restrict__ Qp, const u16* __restrict__ Kp,
                                                 const u16* __restrict__ Vt, u16* __restrict__ O){
  __shared__ u16 sK[2][64 * 128];   // [buf][key][16 slots of 8]; phys slot = s ^ (key&15)   32KB
  __shared__ u16 sV[2][96 * 64];    // [buf][d][8 slots of 8]; phys = s ^ (d&7); d>=72 garbage  24KB
  int tid = threadIdx.x, w = tid >> 6, lane = tid & 63, hi = lane >> 5, l31 = lane & 31;
  int bk = blockIdx.x, qt = blockIdx.y;     // 16 qt-blocks of bk land on XCD bk&7
  int b = bk >> 3, kv = bk & 7;
  int h = (kv << 1) + (w >> 2);
  int q = (qt << 7) + ((w & 3) << 5) + l31;
  const u16* qb = Qp + (size_t)((((b << 4) + h) << 11) + q) * 96;
  s8v qf[5];
  #pragma unroll
  for (int ds = 0; ds < 5; ds++) qf[ds] = *(const s8v*)(qb + ds * 16 + hi * 8);
  f32x16 ao[3] = {};
  float mv = -3.0e38f, lsp = 0.f;
  const char* kb = (const char*)Kp + (size_t)bk * 2048 * 256;
  const char* vb = (const char*)Vt + (size_t)bk * 72 * 4096;
  // K staging: 64 keys x 256B = 1024 chunks of 16B; thread takes n = i*512 + tid, i=0,1
  int ko[2], kd[2];
  #pragma unroll
  for (int i = 0; i < 2; i++){
    int n = i * 512 + tid;
    int kr = n >> 4, sp = n & 15;
    ko[i] = kr * 256 + ((sp ^ (kr & 15)) << 4);
    kd[i] = n << 4;
  }
  // V staging: 72 rows x 128B = 576 chunks; n0 = tid (512), n1 = 512 + lane (w==0 only)
  int vo[2], vd[2];
  #pragma unroll
  for (int i = 0; i < 2; i++){
    int n = (i == 0) ? tid : (512 + lane);
    int vr = n >> 3, sp = n & 7;
    vo[i] = vr * 4096 + ((sp ^ (vr & 7)) << 4);
    vd[i] = n << 4;
  }

#define STAGE(buf, t1) { \
    const char* kt_ = kb + (size_t)(t1) * 16384; \
    gl_lds16(kt_ + ko[0], (char*)sK[buf] + kd[0]); \
    gl_lds16(kt_ + ko[1], (char*)sK[buf] + kd[1]); \
    const char* vt_ = vb + (size_t)(t1) * 128; \
    gl_lds16(vt_ + vo[0], (char*)sV[buf] + vd[0]); \
    if (w == 0) gl_lds16(vt_ + vo[1], (char*)sV[buf] + vd[1]); }

#define MK_PF(S, mlo, PF) { \
      u32 a0 = cvtpk(S[mlo + 0], S[mlo + 1]); \
      u32 a1 = cvtpk(S[mlo + 2], S[mlo + 3]); \
      u32 b0 = cvtpk(S[mlo + 4], S[mlo + 5]); \
      u32 b1 = cvtpk(S[mlo + 6], S[mlo + 7]); \
      asm("v_permlane32_swap_b32 %0, %1" : "+v"(a0), "+v"(b0)); \
      asm("v_permlane32_swap_b32 %0, %1" : "+v"(a1), "+v"(b1)); \
      u32x4 w4 = {a0, a1, b0, b1}; \
      PF = __builtin_bit_cast(s8v, w4); }

  STAGE(0, 0)
  __syncthreads();

  #pragma unroll 1
  for (int t = 0; t < 32; t++){
    int cur = t & 1, nxt = cur ^ 1;
    if (t < 31){ STAGE(nxt, t + 1) }
    const u16* sKc = sK[cur];
    const u16* sVc = sV[cur];
    #pragma unroll
    for (int j = 0; j < 2; j++){
      // ---- QK^T subtile j: C[key][q], keys j*32..j*32+31 ----
      f32x16 sc = {};
      int r = j * 32 + l31;
      __builtin_amdgcn_s_setprio(1);
      #pragma unroll
      for (int ds = 0; ds < 5; ds++){
        int s = ds * 2 + hi;
        s8v kf = *(const s8v*)(sKc + r * 128 + ((s ^ (r & 15)) << 3));
        sc = mfma32(kf, qf[ds], sc);
      }
      __builtin_amdgcn_s_setprio(0);
      // ---- online softmax (exp2 domain): 16 scores/lane, tree reductions ----
      float t8[8];
      #pragma unroll
      for (int i = 0; i < 8; i++) t8[i] = fmaxf(sc[i], sc[i + 8]);
      #pragma unroll
      for (int i = 0; i < 4; i++) t8[i] = fmaxf(t8[i], t8[i + 4]);
      float tm = fmaxf(fmaxf(t8[0], t8[1]), fmaxf(t8[2], t8[3]));
      tm = fmaxf(tm, __shfl_xor(tm, 32));
      if (!__all(tm <= mv + 8.f)){
        float mn = fmaxf(mv, tm);
        float scl = __builtin_amdgcn_exp2f(mv - mn);
        lsp *= scl;
        ao[0] *= scl; ao[1] *= scl; ao[2] *= scl;
        mv = mn;
      }
      float ps[8];
      #pragma unroll
      for (int i = 0; i < 8; i++){
        float e0 = __builtin_amdgcn_exp2f(sc[i] - mv);
        float e1 = __builtin_amdgcn_exp2f(sc[i + 8] - mv);
        sc[i] = e0; sc[i + 8] = e1;
        ps[i] = e0 + e1;
      }
      #pragma unroll
      for (int i = 0; i < 4; i++) ps[i] += ps[i + 4];
      lsp += (ps[0] + ps[1]) + (ps[2] + ps[3]);
      // ---- P -> bf16 B-frags in-register ----
      s8v pfa, pfb;
      MK_PF(sc, 0, pfa)
      MK_PF(sc, 8, pfb)
      // ---- PV subtile j ----
      __builtin_amdgcn_s_setprio(1);
      #pragma unroll
      for (int dt = 0; dt < 3; dt++){
        int rv = dt * 32 + l31;
        int s0 = 4 * j + hi, s1 = 4 * j + 2 + hi;
        s8v vf0 = *(const s8v*)(sVc + rv * 64 + ((s0 ^ (rv & 7)) << 3));
        s8v vf1 = *(const s8v*)(sVc + rv * 64 + ((s1 ^ (rv & 7)) << 3));
        ao[dt] = mfma32(vf0, pfa, ao[dt]);
        ao[dt] = mfma32(vf1, pfb, ao[dt]);
      }
      __builtin_amdgcn_s_setprio(0);
    }
    __syncthreads();
  }
  float ls = lsp + __shfl_xor(lsp, 32);
  float inv = 1.f / ls;
  u16* ob = O + (size_t)((((b << 11) + q) << 4) + h) * 72;
  #pragma unroll
  for (int dt = 0; dt < 3; dt++){
    #pragma unroll
    for (int gp = 0; gp < 4; gp++){
      int d = dt * 32 + gp * 8 + hi * 4;
      if (d < 72){
        u32x2 o2;
        o2.x = cvtpk(ao[dt][gp * 4 + 0] * inv, ao[dt][gp * 4 + 1] * inv);
        o2.y = cvtpk(ao[dt][gp * 4 + 2] * inv, ao[dt][gp * 4 + 3] * inv);
        *(u32x2*)(ob + d) = o2;
      }
    }
  }
#undef STAGE
#undef MK_PF
}

// ---------------- launch ----------------
extern "C" void kernel_launch(void* const* d_in, const int* in_sizes, int n_in,
                              void* d_out, int out_size, void* d_ws, size_t ws_size,
                              hipStream_t stream){
  (void)in_sizes; (void)n_in; (void)out_size; (void)ws_size;
  const float* hs   = (const float*)d_in[0];
  const float* cosp = (const float*)d_in[1];
  const float* sinp = (const float*)d_in[2];
  const float* Wq   = (const float*)d_in[5];
  const float* Wk   = (const float*)d_in[6];
  const float* Wv   = (const float*)d_in[7];
  const float* Wo   = (const float*)d_in[8];
  const float* qnw  = (const float*)d_in[9];
  const float* knw  = (const float*)d_in[10];
  char* ws = (char*)d_ws;
  u16* Xb    = (u16*)(ws);                    // 18,874,368 B (reused as O after gemm1)
  u16* WtQKV = (u16*)(ws + 18874368);         //  5,308,416 B
  u16* Wot   = (u16*)(ws + 24182784);         //  2,654,208 B
  u16* Y     = (u16*)(ws + 26836992);         // 37,748,736 B
  u16* Qp    = (u16*)(ws + 64585728);         // 25,165,824 B (stride 96)
  u16* Kp    = (u16*)(ws + 89751552);         // 16,777,216 B (stride 128)
  u16* Vt    = (u16*)(ws + 106528768);        //  9,437,184 B  (total 115,965,952)
  u16* O     = Xb;

  k_prepx<<<4608, 256, 0, stream>>>(hs, Xb, 8192 * 1152);
  k_transpose<<<36 * 36, 256, 0, stream>>>(Wq, WtQKV, 1152, 1152, 1152);
  k_transpose<<<36 * 18, 256, 0, stream>>>(Wk, WtQKV + 1152 * 1152, 1152, 576, 1152);
  k_transpose<<<36 * 18, 256, 0, stream>>>(Wv, WtQKV + 1728 * 1152, 1152, 576, 1152);
  k_transpose<<<36 * 36, 256, 0, stream>>>(Wo, Wot, 1152, 1152, 1152);
  k_gemm<0><<<dim3(18, 64), 256, 0, stream>>>(Xb, WtQKV, Y, 8192, 2304, 1152);
  k_normrope<<<8192, 192, 0, stream>>>(Y, cosp, sinp, qnw, knw, Qp, Kp);
  k_vtrans<<<dim3(64, 32), 256, 0, stream>>>(Y, Vt);
  k_attn<<<dim3(32, 16), 512, 0, stream>>>(Qp, Kp, Vt, O);
  k_gemm<1><<<dim3(9, 64), 256, 0, stream>>>(O, Wot, (float*)d_out, 8192, 1152, 1152);
}